// Round 7
// baseline (587.862 us; speedup 1.0000x reference)
//
#include <hip/hip_runtime.h>

// GraphSAGE 3-layer inference — R12.
//  * gather: REVERTED to R10 full-row version (R11 column-split regressed
//    62.4 -> ~76.5us/layer; gather is at the ~12B/cy/CU vector-memory
//    ceiling, pattern-bound, parked).
//  * GEMM: B-staging dropped. Bt (<=256KB) is L2-resident and shared by all
//    blocks — read B fragments directly to registers each K-step (counted
//    vmcnt leaves the 2 A-DMA issues in flight; ds_read count halves; DMA
//    drain volume halves). LDS = A-dbuf 16KB + slab alias -> 34816B, still
//    4 blocks/CU.
//  * 3-pass scan, CSR build, prep, final_out unchanged.

#define NN 100000
#define NE 800000
#define MPAD 100096   // 782 * 128

typedef __attribute__((ext_vector_type(8))) short short8;
typedef __attribute__((ext_vector_type(4))) float floatx4;

__device__ __forceinline__ float bf2f(unsigned short u) {
    unsigned int x = ((unsigned int)u) << 16;
    return __builtin_bit_cast(float, x);
}
__device__ __forceinline__ unsigned short f2bf(float f) {
    unsigned int x = __builtin_bit_cast(unsigned int, f);
    x += 0x7fffu + ((x >> 16) & 1u);   // round-to-nearest-even
    return (unsigned short)(x >> 16);
}

// async global->LDS, 16B per lane. LDS dest must be wave-uniform base; HW
// writes base + lane*16. Global src is per-lane.
__device__ __forceinline__ void gl_lds16(const unsigned short* g, unsigned short* l) {
    __builtin_amdgcn_global_load_lds(
        (const __attribute__((address_space(1))) unsigned int*)g,
        (__attribute__((address_space(3))) unsigned int*)l,
        16, 0, 0);
}

// ---------------- CSR build ----------------
__global__ void degi_kernel(const int* __restrict__ dst, int* __restrict__ deg) {
    int e = blockIdx.x * blockDim.x + threadIdx.x;
    if (e < NE) atomicAdd(&deg[dst[e]], 1);
}

// 3-pass exclusive scan of 102400 ints (25600 int4).
__global__ __launch_bounds__(256) void scan1(const int4* __restrict__ deg4,
                                             int4* __restrict__ cur4,
                                             int* __restrict__ bsum) {
    __shared__ int woff[4];
    const int tid = threadIdx.x, lane = tid & 63, w = tid >> 6;
    const int i = blockIdx.x * 256 + tid;
    int4 v = deg4[i];
    int t = v.x + v.y + v.z + v.w;
    int s = t;
    #pragma unroll
    for (int off = 1; off < 64; off <<= 1) {
        int u = __shfl_up(s, off, 64);
        if (lane >= off) s += u;
    }
    if (lane == 63) woff[w] = s;
    __syncthreads();
    if (tid == 0) {
        int a0 = woff[0], a1 = woff[1], a2 = woff[2], a3 = woff[3];
        woff[0] = 0; woff[1] = a0; woff[2] = a0 + a1; woff[3] = a0 + a1 + a2;
        bsum[blockIdx.x] = a0 + a1 + a2 + a3;
    }
    __syncthreads();
    int excl = woff[w] + (s - t);
    int4 o;
    o.x = excl; o.y = o.x + v.x; o.z = o.y + v.y; o.w = o.z + v.z;
    cur4[i] = o;
}

__global__ void scan2(int* __restrict__ bsum) {
    const int lane = threadIdx.x;   // 64 threads
    int carry = 0;
    for (int base = 0; base < 100; base += 64) {
        int n = 100 - base; if (n > 64) n = 64;
        int v = (lane < n) ? bsum[base + lane] : 0;
        int s = v;
        #pragma unroll
        for (int off = 1; off < 64; off <<= 1) {
            int u = __shfl_up(s, off, 64);
            if (lane >= off) s += u;
        }
        int tot = __shfl(s, 63, 64);
        if (lane < n) bsum[base + lane] = carry + s - v;
        carry += tot;
    }
}

__global__ __launch_bounds__(256) void scan3(int4* __restrict__ cur4,
                                             const int* __restrict__ bsum) {
    const int i = blockIdx.x * 256 + threadIdx.x;
    const int o = bsum[blockIdx.x];
    int4 v = cur4[i];
    v.x += o; v.y += o; v.z += o; v.w += o;
    cur4[i] = v;
}

__global__ void scatter_kernel(const int* __restrict__ src, const int* __restrict__ dst,
                               int* __restrict__ cursor, int* __restrict__ nbr) {
    int e = blockIdx.x * blockDim.x + threadIdx.x;
    if (e < NE) {
        int pos = atomicAdd(&cursor[dst[e]], 1);
        nbr[pos] = src[e];
    }
}

// ---------------- casts / weight prep ----------------
__global__ void cast_x_kernel(const float4* __restrict__ x, unsigned short* __restrict__ H) {
    int gid = blockIdx.x * 256 + threadIdx.x;   // NN*64 float4 groups
    if (gid >= NN * 64) return;
    int row = gid >> 6, col = (gid & 63) * 4;
    float4 v = x[gid];
    ushort4 o;
    o.x = f2bf(v.x); o.y = f2bf(v.y); o.z = f2bf(v.z); o.w = f2bf(v.w);
    *(ushort4*)&H[(size_t)row * 512 + col] = o;
}

// Bt[n][k] = bf16( k<256 ? Ws[k][n] : Wn[k-256][n] ),  [256][512]
__global__ void wprep_kernel(const float* __restrict__ Ws, const float* __restrict__ Wn,
                             unsigned short* __restrict__ Bt) {
    int idx = blockIdx.x * 256 + threadIdx.x;
    if (idx >= 256 * 512) return;
    int n = idx >> 9, k = idx & 511;
    float v = (k < 256) ? Ws[(size_t)k * 256 + n] : Wn[(size_t)(k - 256) * 256 + n];
    Bt[idx] = f2bf(v);
}

// Bt3[n][k] (n<128, k<256): n<64 -> Ws3[k][n], else Wn3[k][n-64]; b3ext = [b3 | 0]
__global__ void wprep3_kernel(const float* __restrict__ Ws3, const float* __restrict__ Wn3,
                              const float* __restrict__ b3, unsigned short* __restrict__ Bt3,
                              float* __restrict__ b3ext) {
    int idx = blockIdx.x * 256 + threadIdx.x;
    if (idx < 128 * 256) {
        int n = idx >> 8, k = idx & 255;
        float v = (n < 64) ? Ws3[(size_t)k * 64 + n] : Wn3[(size_t)k * 64 + (n - 64)];
        Bt3[idx] = f2bf(v);
    }
    if (idx < 128) b3ext[idx] = (idx < 64) ? b3[idx] : 0.f;
}

// ---------------- pull-mean gather: wave/node, LDS-prefetched indices ----------------
__global__ __launch_bounds__(256) void gather_bf16(unsigned short* __restrict__ H,
                                                   const int* __restrict__ nbr,
                                                   const int* __restrict__ cursor,
                                                   const int* __restrict__ deg) {
    __shared__ int sidx[4][64];
    const int lane = threadIdx.x & 63;
    const int sub  = threadIdx.x >> 6;
    const int d = blockIdx.x * 4 + sub;
    if (d >= NN) return;
    const int dg = deg[d];
    const int end = cursor[d];
    const int start = end - dg;
    const int co = lane * 4;          // shorts 4*lane .. +4 of the 256-short left half
    const int dgc = (dg < 64) ? dg : 64;

    if (lane < dgc) sidx[sub][lane] = nbr[start + lane];
    const int* si = sidx[sub];

    float acc[4] = {0.f, 0.f, 0.f, 0.f};

    int r = 0;
    for (; r + 8 <= dgc; r += 8) {     // 8 rows (4KB) in flight
        int s0 = si[r + 0], s1 = si[r + 1], s2 = si[r + 2], s3 = si[r + 3];
        int s4 = si[r + 4], s5 = si[r + 5], s6 = si[r + 6], s7 = si[r + 7];
        ushort4 v0 = *(const ushort4*)&H[(size_t)s0 * 512 + co];
        ushort4 v1 = *(const ushort4*)&H[(size_t)s1 * 512 + co];
        ushort4 v2 = *(const ushort4*)&H[(size_t)s2 * 512 + co];
        ushort4 v3 = *(const ushort4*)&H[(size_t)s3 * 512 + co];
        ushort4 v4 = *(const ushort4*)&H[(size_t)s4 * 512 + co];
        ushort4 v5 = *(const ushort4*)&H[(size_t)s5 * 512 + co];
        ushort4 v6 = *(const ushort4*)&H[(size_t)s6 * 512 + co];
        ushort4 v7 = *(const ushort4*)&H[(size_t)s7 * 512 + co];
        acc[0] += (bf2f(v0.x) + bf2f(v1.x)) + (bf2f(v2.x) + bf2f(v3.x))
                + (bf2f(v4.x) + bf2f(v5.x)) + (bf2f(v6.x) + bf2f(v7.x));
        acc[1] += (bf2f(v0.y) + bf2f(v1.y)) + (bf2f(v2.y) + bf2f(v3.y))
                + (bf2f(v4.y) + bf2f(v5.y)) + (bf2f(v6.y) + bf2f(v7.y));
        acc[2] += (bf2f(v0.z) + bf2f(v1.z)) + (bf2f(v2.z) + bf2f(v3.z))
                + (bf2f(v4.z) + bf2f(v5.z)) + (bf2f(v6.z) + bf2f(v7.z));
        acc[3] += (bf2f(v0.w) + bf2f(v1.w)) + (bf2f(v2.w) + bf2f(v3.w))
                + (bf2f(v4.w) + bf2f(v5.w)) + (bf2f(v6.w) + bf2f(v7.w));
    }
    for (; r + 4 <= dgc; r += 4) {
        int s0 = si[r + 0], s1 = si[r + 1], s2 = si[r + 2], s3 = si[r + 3];
        ushort4 v0 = *(const ushort4*)&H[(size_t)s0 * 512 + co];
        ushort4 v1 = *(const ushort4*)&H[(size_t)s1 * 512 + co];
        ushort4 v2 = *(const ushort4*)&H[(size_t)s2 * 512 + co];
        ushort4 v3 = *(const ushort4*)&H[(size_t)s3 * 512 + co];
        acc[0] += (bf2f(v0.x) + bf2f(v1.x)) + (bf2f(v2.x) + bf2f(v3.x));
        acc[1] += (bf2f(v0.y) + bf2f(v1.y)) + (bf2f(v2.y) + bf2f(v3.y));
        acc[2] += (bf2f(v0.z) + bf2f(v1.z)) + (bf2f(v2.z) + bf2f(v3.z));
        acc[3] += (bf2f(v0.w) + bf2f(v1.w)) + (bf2f(v2.w) + bf2f(v3.w));
    }
    for (; r < dgc; ++r) {
        int s0 = si[r];
        ushort4 v0 = *(const ushort4*)&H[(size_t)s0 * 512 + co];
        acc[0] += bf2f(v0.x); acc[1] += bf2f(v0.y);
        acc[2] += bf2f(v0.z); acc[3] += bf2f(v0.w);
    }
    for (int j = start + 64; j < end; ++j) {   // deg>64 tail (practically never)
        int s0 = nbr[j];
        ushort4 v0 = *(const ushort4*)&H[(size_t)s0 * 512 + co];
        acc[0] += bf2f(v0.x); acc[1] += bf2f(v0.y);
        acc[2] += bf2f(v0.z); acc[3] += bf2f(v0.w);
    }

    const float inv = 1.0f / fmaxf((float)dg, 1.0f);
    ushort4 o;
    o.x = f2bf(acc[0] * inv); o.y = f2bf(acc[1] * inv);
    o.z = f2bf(acc[2] * inv); o.w = f2bf(acc[3] * inv);
    *(ushort4*)&H[(size_t)d * 512 + 256 + co] = o;
}

// ---------------- bf16 MFMA GEMM: A via LDS dbuf (slot-XOR), B direct-to-reg ----------------
// C[128 x 128 per block] = A[., K] @ Bt^T + bias. KT = K/32.
// A LDS tile [128][32] shorts, slot-XOR swizzled (LDS[row][slot] =
// global[row][slot ^ (row&3)], 16B slots) on both the DMA source and the
// ds_read address. B fragments read straight from global (L2-resident,
// <=256KB shared by all blocks) — counted vmcnt leaves A-DMA in flight.
template <int KT, bool RELU>
__global__ __launch_bounds__(256, 4) void sage_mfma(const unsigned short* __restrict__ A,
                                                    const unsigned short* __restrict__ Bt,
                                                    const float* __restrict__ bias,
                                                    unsigned short* __restrict__ Cout, int ldc) {
    __shared__ unsigned short lds[17408];   // A dbuf 2x4096 shorts; slab alias 17408
    constexpr int BSTR = KT * 32;           // Bt row stride in shorts
    const int tid = threadIdx.x;
    const int lane = tid & 63;
    const int w = tid >> 6, wm = w >> 1, wn = w & 1;
    const int m0 = blockIdx.x * 128, n0 = blockIdx.y * 128;
    const int lr = lane & 15, lq = lane >> 4;

    // A staging: wave w owns rows [w*32, w*32+32); lane l covers row +(l>>2),
    // source slot (l&3)^(row&3).
    const int sr   = lane >> 2;                       // 0..15 within 16-row chunk
    const int ssl  = (lane & 3) ^ (sr & 3);           // swizzled source slot
    const unsigned short* gA = A + (size_t)(m0 + w * 32 + sr) * 512 + ssl * 8;

    // B direct: per-lane fragment base (row n0+wn*64+lr, 16B chunk lq)
    const unsigned short* gB = Bt + (size_t)(n0 + wn * 64 + lr) * BSTR + lq * 8;

    const int lqx = (lq ^ (lr & 3)) * 8;   // read-side swizzled slot (shorts)

    floatx4 acc[4][4] = {};

    // prologue: stage A step 0 into buf 0
    {
        unsigned short* lA = &lds[(w * 32) * 32];
        gl_lds16(gA,                       lA);
        gl_lds16(gA + (size_t)16 * 512,    lA + 512);
    }
    __syncthreads();

    #pragma unroll
    for (int t = 0; t < KT; ++t) {
        const int buf = t & 1;
        // B(t) fragments to registers (issued before A-DMA so the MFMA's
        // vmcnt wait is counted, leaving the 2 DMA issues in flight)
        short8 bf[4];
        #pragma unroll
        for (int ni = 0; ni < 4; ++ni)
            bf[ni] = *(const short8*)(gB + (size_t)ni * 16 * BSTR + t * 32);
        // A-DMA for step t+1
        if (t + 1 < KT) {
            unsigned short* lA = &lds[(buf ^ 1) * 4096 + (w * 32) * 32];
            const unsigned short* pA = gA + (size_t)(t + 1) * 32;
            gl_lds16(pA,                    lA);
            gl_lds16(pA + (size_t)16 * 512, lA + 512);
        }
        // A(t) fragments from LDS
        const unsigned short* bA = &lds[buf * 4096];
        short8 af[4];
        #pragma unroll
        for (int mi = 0; mi < 4; ++mi)
            af[mi] = *(const short8*)&bA[(wm * 64 + mi * 16 + lr) * 32 + lqx];
        #pragma unroll
        for (int mi = 0; mi < 4; ++mi)
            #pragma unroll
            for (int ni = 0; ni < 4; ++ni)
                acc[mi][ni] = __builtin_amdgcn_mfma_f32_16x16x32_bf16(bf[ni], af[mi],
                                                                      acc[mi][ni], 0, 0, 0);
        __syncthreads();   // drains this step's DMA + ds_reads before buf reuse
    }

    // Epilogue: bias + (relu) + bf16 -> LDS slab -> coalesced 16B stores.
    unsigned short* slab = &lds[0];   // 128*136 shorts = 17408
    #pragma unroll
    for (int mi = 0; mi < 4; ++mi) {
        const int rl = wm * 64 + mi * 16 + lr;
        #pragma unroll
        for (int ni = 0; ni < 4; ++ni) {
            const int cl = wn * 64 + ni * 16 + lq * 4;
            const float4 bv = *(const float4*)&bias[n0 + cl];
            float v0 = acc[mi][ni][0] + bv.x;
            float v1 = acc[mi][ni][1] + bv.y;
            float v2 = acc[mi][ni][2] + bv.z;
            float v3 = acc[mi][ni][3] + bv.w;
            if (RELU) {
                v0 = fmaxf(v0, 0.f); v1 = fmaxf(v1, 0.f);
                v2 = fmaxf(v2, 0.f); v3 = fmaxf(v3, 0.f);
            }
            ushort4 o;
            o.x = f2bf(v0); o.y = f2bf(v1); o.z = f2bf(v2); o.w = f2bf(v3);
            *(ushort4*)&slab[rl * 136 + cl] = o;
        }
    }
    __syncthreads();
    #pragma unroll
    for (int it = 0; it < 8; ++it) {
        int idx = it * 256 + tid;
        int row = idx >> 4, c8 = (idx & 15) * 8;
        if (m0 + row < NN) {
            short8 v = *(const short8*)&slab[row * 136 + c8];
            *(short8*)&Cout[(size_t)(m0 + row) * ldc + n0 + c8] = v;
        }
    }
}

// ---------------- layer-3 finalize: out = S + mean_agg(P) ----------------
__global__ __launch_bounds__(256) void final_out(const unsigned short* __restrict__ T,
                                                 const int* __restrict__ nbr,
                                                 const int* __restrict__ cursor,
                                                 const int* __restrict__ deg,
                                                 float* __restrict__ out) {
    __shared__ int sidx[4][64];
    const int lane = threadIdx.x & 63;
    const int sub  = threadIdx.x >> 6;
    const int d = blockIdx.x * 4 + sub;
    if (d >= NN) return;
    const int g  = lane >> 4;         // edge group 0..3
    const int li = lane & 15;         // column li*4 .. +4
    const int dg = deg[d];
    const int end = cursor[d];
    const int start = end - dg;
    const int co = li * 4;
    const int dgc = (dg < 64) ? dg : 64;

    ushort4 sv = *(const ushort4*)&T[(size_t)d * 128 + co];

    if (lane < dgc) sidx[sub][lane] = nbr[start + lane];
    const int* si = sidx[sub];

    float acc[4] = {0.f, 0.f, 0.f, 0.f};
    int r = g;
    for (; r + 4 < dgc; r += 8) {
        int s0 = si[r], s1 = si[r + 4];
        ushort4 v0 = *(const ushort4*)&T[(size_t)s0 * 128 + 64 + co];
        ushort4 v1 = *(const ushort4*)&T[(size_t)s1 * 128 + 64 + co];
        acc[0] += bf2f(v0.x) + bf2f(v1.x);
        acc[1] += bf2f(v0.y) + bf2f(v1.y);
        acc[2] += bf2f(v0.z) + bf2f(v1.z);
        acc[3] += bf2f(v0.w) + bf2f(v1.w);
    }
    for (; r < dgc; r += 4) {
        int s0 = si[r];
        ushort4 v0 = *(const ushort4*)&T[(size_t)s0 * 128 + 64 + co];
        acc[0] += bf2f(v0.x); acc[1] += bf2f(v0.y);
        acc[2] += bf2f(v0.z); acc[3] += bf2f(v0.w);
    }
    for (int j = start + 64 + g; j < end; j += 4) {   // deg>64 tail
        int s0 = nbr[j];
        ushort4 v0 = *(const ushort4*)&T[(size_t)s0 * 128 + 64 + co];
        acc[0] += bf2f(v0.x); acc[1] += bf2f(v0.y);
        acc[2] += bf2f(v0.z); acc[3] += bf2f(v0.w);
    }

    #pragma unroll
    for (int i = 0; i < 4; ++i) {
        acc[i] += __shfl_xor(acc[i], 16, 64);
        acc[i] += __shfl_xor(acc[i], 32, 64);
    }

    if (g == 0) {
        const float inv = 1.0f / fmaxf((float)dg, 1.0f);
        float4 o;
        o.x = bf2f(sv.x) + acc[0] * inv;
        o.y = bf2f(sv.y) + acc[1] * inv;
        o.z = bf2f(sv.z) + acc[2] * inv;
        o.w = bf2f(sv.w) + acc[3] * inv;
        *(float4*)&out[(size_t)d * 64 + co] = o;
    }
}

extern "C" void kernel_launch(void* const* d_in, const int* in_sizes, int n_in,
                              void* d_out, int out_size, void* d_ws, size_t ws_size,
                              hipStream_t stream) {
    const float* x   = (const float*)d_in[0];
    const int*   src = (const int*)d_in[1];
    const int*   dst = (const int*)d_in[2];
    const float* Ws1 = (const float*)d_in[3];
    const float* Wn1 = (const float*)d_in[4];
    const float* b1  = (const float*)d_in[5];
    const float* Ws2 = (const float*)d_in[6];
    const float* Wn2 = (const float*)d_in[7];
    const float* b2  = (const float*)d_in[8];
    const float* Ws3 = (const float*)d_in[9];
    const float* Wn3 = (const float*)d_in[10];
    const float* b3  = (const float*)d_in[11];

    unsigned short* H1  = (unsigned short*)d_ws;
    unsigned short* H2  = H1  + (size_t)MPAD * 512;
    unsigned short* T   = H2  + (size_t)MPAD * 512;
    unsigned short* Bt1 = T   + (size_t)MPAD * 128;
    unsigned short* Bt2 = Bt1 + 256 * 512;
    unsigned short* Bt3 = Bt2 + 256 * 512;
    float* b3ext = (float*)(Bt3 + 128 * 256);
    int* deg    = (int*)(b3ext + 128);
    int* cursor = deg + 102400;
    int* nbr    = cursor + 102400;
    int* bsum   = nbr + NE;           // 100 ints (+pad)

    // CSR build (graph shared by all layers); pad region zeroed for int4 scan.
    hipMemsetAsync(deg, 0, 102400 * sizeof(int), stream);
    degi_kernel<<<(NE + 255) / 256, 256, 0, stream>>>(dst, deg);
    scan1<<<100, 256, 0, stream>>>((const int4*)deg, (int4*)cursor, bsum);
    scan2<<<1, 64, 0, stream>>>(bsum);
    scan3<<<100, 256, 0, stream>>>((int4*)cursor, bsum);
    scatter_kernel<<<(NE + 255) / 256, 256, 0, stream>>>(src, dst, cursor, nbr);
    // cursor[d] = end offset; bucket d = nbr[end-deg .. end)

    // bf16 prep
    cast_x_kernel<<<(NN * 64 + 255) / 256, 256, 0, stream>>>((const float4*)x, H1);
    wprep_kernel<<<512, 256, 0, stream>>>(Ws1, Wn1, Bt1);
    wprep_kernel<<<512, 256, 0, stream>>>(Ws2, Wn2, Bt2);
    wprep3_kernel<<<128, 256, 0, stream>>>(Ws3, Wn3, b3, Bt3, b3ext);

    const int gatherBlocks = (NN + 3) / 4;
    const dim3 g2(MPAD / 128, 2), g1(MPAD / 128, 1);

    // layer 1: H1 -> H2(left)
    gather_bf16<<<gatherBlocks, 256, 0, stream>>>(H1, nbr, cursor, deg);
    sage_mfma<16, true><<<g2, 256, 0, stream>>>(H1, Bt1, b1, H2, 512);

    // layer 2: H2 -> H1(left)
    gather_bf16<<<gatherBlocks, 256, 0, stream>>>(H2, nbr, cursor, deg);
    sage_mfma<16, true><<<g2, 256, 0, stream>>>(H2, Bt2, b2, H1, 512);

    // layer 3: T = [H1@Ws3+b3 | H1@Wn3] (K=256), then out = S + agg(P)
    sage_mfma<8, false><<<g1, 256, 0, stream>>>(H1, Bt3, b3ext, T, 128);
    final_out<<<gatherBlocks, 256, 0, stream>>>(T, nbr, cursor, deg, (float*)d_out);
}

// Round 8
// 519.955 us; speedup vs baseline: 1.1306x; 1.1306x over previous
//
#include <hip/hip_runtime.h>

// GraphSAGE 3-layer inference — R13.
//  * GEMM: reverted to R10 (BK=32 dbuf via global_load_lds for BOTH A and B,
//    slot-XOR swizzle, 4 blocks/CU). R12's B-direct-to-reg regressed 533->588:
//    in-loop register-consumed B loads expose L2 latency every K-step
//    (MfmaUtil 12.6%, bank conflicts 2.2M).
//  * degi fused into cast_x (edge atomics ride the 150MB streaming cast).
//  * wprep1/2/3 fused into one dispatch.
//  * gather/final_out (pattern-bound per R9/R11), 3-pass scan unchanged.

#define NN 100000
#define NE 800000
#define MPAD 100096   // 782 * 128

typedef __attribute__((ext_vector_type(8))) short short8;
typedef __attribute__((ext_vector_type(4))) float floatx4;

__device__ __forceinline__ float bf2f(unsigned short u) {
    unsigned int x = ((unsigned int)u) << 16;
    return __builtin_bit_cast(float, x);
}
__device__ __forceinline__ unsigned short f2bf(float f) {
    unsigned int x = __builtin_bit_cast(unsigned int, f);
    x += 0x7fffu + ((x >> 16) & 1u);   // round-to-nearest-even
    return (unsigned short)(x >> 16);
}

// async global->LDS, 16B per lane. LDS dest must be wave-uniform base; HW
// writes base + lane*16. Global src is per-lane.
__device__ __forceinline__ void gl_lds16(const unsigned short* g, unsigned short* l) {
    __builtin_amdgcn_global_load_lds(
        (const __attribute__((address_space(1))) unsigned int*)g,
        (__attribute__((address_space(3))) unsigned int*)l,
        16, 0, 0);
}

// ---------------- fused cast + degree count ----------------
// cast: x[NN][256] f32 -> H left half bf16. First NE threads also count
// in-degrees (atomics overlap the streaming cast).
__global__ __launch_bounds__(256) void cast_degi(const float4* __restrict__ x,
                                                 unsigned short* __restrict__ H,
                                                 const int* __restrict__ dst,
                                                 int* __restrict__ deg) {
    int gid = blockIdx.x * 256 + threadIdx.x;   // NN*64 float4 groups
    if (gid < NE) atomicAdd(&deg[dst[gid]], 1);
    if (gid >= NN * 64) return;
    int row = gid >> 6, col = (gid & 63) * 4;
    float4 v = x[gid];
    ushort4 o;
    o.x = f2bf(v.x); o.y = f2bf(v.y); o.z = f2bf(v.z); o.w = f2bf(v.w);
    *(ushort4*)&H[(size_t)row * 512 + col] = o;
}

// 3-pass exclusive scan of 102400 ints (25600 int4).
__global__ __launch_bounds__(256) void scan1(const int4* __restrict__ deg4,
                                             int4* __restrict__ cur4,
                                             int* __restrict__ bsum) {
    __shared__ int woff[4];
    const int tid = threadIdx.x, lane = tid & 63, w = tid >> 6;
    const int i = blockIdx.x * 256 + tid;
    int4 v = deg4[i];
    int t = v.x + v.y + v.z + v.w;
    int s = t;
    #pragma unroll
    for (int off = 1; off < 64; off <<= 1) {
        int u = __shfl_up(s, off, 64);
        if (lane >= off) s += u;
    }
    if (lane == 63) woff[w] = s;
    __syncthreads();
    if (tid == 0) {
        int a0 = woff[0], a1 = woff[1], a2 = woff[2], a3 = woff[3];
        woff[0] = 0; woff[1] = a0; woff[2] = a0 + a1; woff[3] = a0 + a1 + a2;
        bsum[blockIdx.x] = a0 + a1 + a2 + a3;
    }
    __syncthreads();
    int excl = woff[w] + (s - t);
    int4 o;
    o.x = excl; o.y = o.x + v.x; o.z = o.y + v.y; o.w = o.z + v.z;
    cur4[i] = o;
}

__global__ void scan2(int* __restrict__ bsum) {
    const int lane = threadIdx.x;   // 64 threads
    int carry = 0;
    for (int base = 0; base < 100; base += 64) {
        int n = 100 - base; if (n > 64) n = 64;
        int v = (lane < n) ? bsum[base + lane] : 0;
        int s = v;
        #pragma unroll
        for (int off = 1; off < 64; off <<= 1) {
            int u = __shfl_up(s, off, 64);
            if (lane >= off) s += u;
        }
        int tot = __shfl(s, 63, 64);
        if (lane < n) bsum[base + lane] = carry + s - v;
        carry += tot;
    }
}

__global__ __launch_bounds__(256) void scan3(int4* __restrict__ cur4,
                                             const int* __restrict__ bsum) {
    const int i = blockIdx.x * 256 + threadIdx.x;
    const int o = bsum[blockIdx.x];
    int4 v = cur4[i];
    v.x += o; v.y += o; v.z += o; v.w += o;
    cur4[i] = v;
}

__global__ void scatter_kernel(const int* __restrict__ src, const int* __restrict__ dst,
                               int* __restrict__ cursor, int* __restrict__ nbr) {
    int e = blockIdx.x * blockDim.x + threadIdx.x;
    if (e < NE) {
        int pos = atomicAdd(&cursor[dst[e]], 1);
        nbr[pos] = src[e];
    }
}

// ---------------- fused weight prep (layers 1,2,3 in one dispatch) ----------------
// blocks [0,512): Bt1; [512,1024): Bt2; [1024,1152): Bt3 + b3ext.
__global__ __launch_bounds__(256) void wprep_all(
        const float* __restrict__ Ws1, const float* __restrict__ Wn1,
        const float* __restrict__ Ws2, const float* __restrict__ Wn2,
        const float* __restrict__ Ws3, const float* __restrict__ Wn3,
        const float* __restrict__ b3,
        unsigned short* __restrict__ Bt1, unsigned short* __restrict__ Bt2,
        unsigned short* __restrict__ Bt3, float* __restrict__ b3ext) {
    const int b = blockIdx.x;
    if (b < 1024) {
        const float* Ws = (b < 512) ? Ws1 : Ws2;
        const float* Wn = (b < 512) ? Wn1 : Wn2;
        unsigned short* Bt = (b < 512) ? Bt1 : Bt2;
        int idx = ((b & 511) << 8) + threadIdx.x;     // 0 .. 256*512
        int n = idx >> 9, k = idx & 511;
        float v = (k < 256) ? Ws[(size_t)k * 256 + n] : Wn[(size_t)(k - 256) * 256 + n];
        Bt[idx] = f2bf(v);
    } else {
        int idx = ((b - 1024) << 8) + threadIdx.x;    // 0 .. 128*256
        int n = idx >> 8, k = idx & 255;
        float v = (n < 64) ? Ws3[(size_t)k * 64 + n] : Wn3[(size_t)k * 64 + (n - 64)];
        Bt3[idx] = f2bf(v);
        if (idx < 128) b3ext[idx] = (idx < 64) ? b3[idx] : 0.f;
    }
}

// ---------------- pull-mean gather: wave/node, LDS-prefetched indices ----------------
__global__ __launch_bounds__(256) void gather_bf16(unsigned short* __restrict__ H,
                                                   const int* __restrict__ nbr,
                                                   const int* __restrict__ cursor,
                                                   const int* __restrict__ deg) {
    __shared__ int sidx[4][64];
    const int lane = threadIdx.x & 63;
    const int sub  = threadIdx.x >> 6;
    const int d = blockIdx.x * 4 + sub;
    if (d >= NN) return;
    const int dg = deg[d];
    const int end = cursor[d];
    const int start = end - dg;
    const int co = lane * 4;          // shorts 4*lane .. +4 of the 256-short left half
    const int dgc = (dg < 64) ? dg : 64;

    if (lane < dgc) sidx[sub][lane] = nbr[start + lane];
    const int* si = sidx[sub];

    float acc[4] = {0.f, 0.f, 0.f, 0.f};

    int r = 0;
    for (; r + 8 <= dgc; r += 8) {     // 8 rows (4KB) in flight
        int s0 = si[r + 0], s1 = si[r + 1], s2 = si[r + 2], s3 = si[r + 3];
        int s4 = si[r + 4], s5 = si[r + 5], s6 = si[r + 6], s7 = si[r + 7];
        ushort4 v0 = *(const ushort4*)&H[(size_t)s0 * 512 + co];
        ushort4 v1 = *(const ushort4*)&H[(size_t)s1 * 512 + co];
        ushort4 v2 = *(const ushort4*)&H[(size_t)s2 * 512 + co];
        ushort4 v3 = *(const ushort4*)&H[(size_t)s3 * 512 + co];
        ushort4 v4 = *(const ushort4*)&H[(size_t)s4 * 512 + co];
        ushort4 v5 = *(const ushort4*)&H[(size_t)s5 * 512 + co];
        ushort4 v6 = *(const ushort4*)&H[(size_t)s6 * 512 + co];
        ushort4 v7 = *(const ushort4*)&H[(size_t)s7 * 512 + co];
        acc[0] += (bf2f(v0.x) + bf2f(v1.x)) + (bf2f(v2.x) + bf2f(v3.x))
                + (bf2f(v4.x) + bf2f(v5.x)) + (bf2f(v6.x) + bf2f(v7.x));
        acc[1] += (bf2f(v0.y) + bf2f(v1.y)) + (bf2f(v2.y) + bf2f(v3.y))
                + (bf2f(v4.y) + bf2f(v5.y)) + (bf2f(v6.y) + bf2f(v7.y));
        acc[2] += (bf2f(v0.z) + bf2f(v1.z)) + (bf2f(v2.z) + bf2f(v3.z))
                + (bf2f(v4.z) + bf2f(v5.z)) + (bf2f(v6.z) + bf2f(v7.z));
        acc[3] += (bf2f(v0.w) + bf2f(v1.w)) + (bf2f(v2.w) + bf2f(v3.w))
                + (bf2f(v4.w) + bf2f(v5.w)) + (bf2f(v6.w) + bf2f(v7.w));
    }
    for (; r + 4 <= dgc; r += 4) {
        int s0 = si[r + 0], s1 = si[r + 1], s2 = si[r + 2], s3 = si[r + 3];
        ushort4 v0 = *(const ushort4*)&H[(size_t)s0 * 512 + co];
        ushort4 v1 = *(const ushort4*)&H[(size_t)s1 * 512 + co];
        ushort4 v2 = *(const ushort4*)&H[(size_t)s2 * 512 + co];
        ushort4 v3 = *(const ushort4*)&H[(size_t)s3 * 512 + co];
        acc[0] += (bf2f(v0.x) + bf2f(v1.x)) + (bf2f(v2.x) + bf2f(v3.x));
        acc[1] += (bf2f(v0.y) + bf2f(v1.y)) + (bf2f(v2.y) + bf2f(v3.y));
        acc[2] += (bf2f(v0.z) + bf2f(v1.z)) + (bf2f(v2.z) + bf2f(v3.z));
        acc[3] += (bf2f(v0.w) + bf2f(v1.w)) + (bf2f(v2.w) + bf2f(v3.w));
    }
    for (; r < dgc; ++r) {
        int s0 = si[r];
        ushort4 v0 = *(const ushort4*)&H[(size_t)s0 * 512 + co];
        acc[0] += bf2f(v0.x); acc[1] += bf2f(v0.y);
        acc[2] += bf2f(v0.z); acc[3] += bf2f(v0.w);
    }
    for (int j = start + 64; j < end; ++j) {   // deg>64 tail (practically never)
        int s0 = nbr[j];
        ushort4 v0 = *(const ushort4*)&H[(size_t)s0 * 512 + co];
        acc[0] += bf2f(v0.x); acc[1] += bf2f(v0.y);
        acc[2] += bf2f(v0.z); acc[3] += bf2f(v0.w);
    }

    const float inv = 1.0f / fmaxf((float)dg, 1.0f);
    ushort4 o;
    o.x = f2bf(acc[0] * inv); o.y = f2bf(acc[1] * inv);
    o.z = f2bf(acc[2] * inv); o.w = f2bf(acc[3] * inv);
    *(ushort4*)&H[(size_t)d * 512 + 256 + co] = o;
}

// ---------------- bf16 MFMA GEMM: BK=32 dbuf, 4 blocks/CU, slot-XOR swizzle ----------------
// C[128 x 128 per block] = A[., K] @ Bt^T + bias. KT = K/32.
// LDS tile [128][32] shorts (64B rows). Slot-XOR: LDS[row][slot] holds
// global[row][slot ^ (row&3)] (16B slots); applied on the global SOURCE of
// global_load_lds and on the ds_read address -> 16-way conflict becomes 4-way.
template <int KT, bool RELU>
__global__ __launch_bounds__(256, 4) void sage_mfma(const unsigned short* __restrict__ A,
                                                    const unsigned short* __restrict__ Bt,
                                                    const float* __restrict__ bias,
                                                    unsigned short* __restrict__ Cout, int ldc) {
    __shared__ unsigned short lds[17408];   // 34816 B: dbuf 2x2x4096 shorts; slab 17408
    constexpr int BSTR = KT * 32;           // Bt row stride in shorts
    const int tid = threadIdx.x;
    const int lane = tid & 63;
    const int w = tid >> 6, wm = w >> 1, wn = w & 1;
    const int m0 = blockIdx.x * 128, n0 = blockIdx.y * 128;
    const int lr = lane & 15, lq = lane >> 4;

    const int sr   = lane >> 2;                       // 0..15 within 16-row chunk
    const int ssl  = (lane & 3) ^ (sr & 3);           // swizzled source slot
    const unsigned short* gA = A  + (size_t)(m0 + w * 32 + sr) * 512  + ssl * 8;
    const unsigned short* gB = Bt + (size_t)(n0 + w * 32 + sr) * BSTR + ssl * 8;

    const int lqx = (lq ^ (lr & 3)) * 8;   // read-side swizzled slot (shorts)

    floatx4 acc[4][4] = {};

    {
        unsigned short* lA = &lds[0 * 8192 + (w * 32) * 32];
        unsigned short* lB = &lds[0 * 8192 + 4096 + (w * 32) * 32];
        #pragma unroll
        for (int c = 0; c < 2; ++c) {
            gl_lds16(gA + (size_t)c * 16 * 512,  lA + c * 512);
            gl_lds16(gB + (size_t)c * 16 * BSTR, lB + c * 512);
        }
    }
    __syncthreads();

    #pragma unroll
    for (int t = 0; t < KT; ++t) {
        const int buf = t & 1;
        if (t + 1 < KT) {
            unsigned short* lA = &lds[(buf ^ 1) * 8192 + (w * 32) * 32];
            unsigned short* lB = &lds[(buf ^ 1) * 8192 + 4096 + (w * 32) * 32];
            const unsigned short* pA = gA + (size_t)(t + 1) * 32;
            const unsigned short* pB = gB + (size_t)(t + 1) * 32;
            #pragma unroll
            for (int c = 0; c < 2; ++c) {
                gl_lds16(pA + (size_t)c * 16 * 512,  lA + c * 512);
                gl_lds16(pB + (size_t)c * 16 * BSTR, lB + c * 512);
            }
        }
        const unsigned short* bA = &lds[buf * 8192];
        const unsigned short* bB = bA + 4096;
        short8 af[4], bf[4];
        #pragma unroll
        for (int mi = 0; mi < 4; ++mi)
            af[mi] = *(const short8*)&bA[(wm * 64 + mi * 16 + lr) * 32 + lqx];
        #pragma unroll
        for (int ni = 0; ni < 4; ++ni)
            bf[ni] = *(const short8*)&bB[(wn * 64 + ni * 16 + lr) * 32 + lqx];
        #pragma unroll
        for (int mi = 0; mi < 4; ++mi)
            #pragma unroll
            for (int ni = 0; ni < 4; ++ni)
                acc[mi][ni] = __builtin_amdgcn_mfma_f32_16x16x32_bf16(bf[ni], af[mi],
                                                                      acc[mi][ni], 0, 0, 0);
        __syncthreads();
    }

    unsigned short* slab = &lds[0];   // 128*136 shorts = 17408
    #pragma unroll
    for (int mi = 0; mi < 4; ++mi) {
        const int rl = wm * 64 + mi * 16 + lr;
        #pragma unroll
        for (int ni = 0; ni < 4; ++ni) {
            const int cl = wn * 64 + ni * 16 + lq * 4;
            const float4 bv = *(const float4*)&bias[n0 + cl];
            float v0 = acc[mi][ni][0] + bv.x;
            float v1 = acc[mi][ni][1] + bv.y;
            float v2 = acc[mi][ni][2] + bv.z;
            float v3 = acc[mi][ni][3] + bv.w;
            if (RELU) {
                v0 = fmaxf(v0, 0.f); v1 = fmaxf(v1, 0.f);
                v2 = fmaxf(v2, 0.f); v3 = fmaxf(v3, 0.f);
            }
            ushort4 o;
            o.x = f2bf(v0); o.y = f2bf(v1); o.z = f2bf(v2); o.w = f2bf(v3);
            *(ushort4*)&slab[rl * 136 + cl] = o;
        }
    }
    __syncthreads();
    #pragma unroll
    for (int it = 0; it < 8; ++it) {
        int idx = it * 256 + tid;
        int row = idx >> 4, c8 = (idx & 15) * 8;
        if (m0 + row < NN) {
            short8 v = *(const short8*)&slab[row * 136 + c8];
            *(short8*)&Cout[(size_t)(m0 + row) * ldc + n0 + c8] = v;
        }
    }
}

// ---------------- layer-3 finalize: out = S + mean_agg(P) ----------------
__global__ __launch_bounds__(256) void final_out(const unsigned short* __restrict__ T,
                                                 const int* __restrict__ nbr,
                                                 const int* __restrict__ cursor,
                                                 const int* __restrict__ deg,
                                                 float* __restrict__ out) {
    __shared__ int sidx[4][64];
    const int lane = threadIdx.x & 63;
    const int sub  = threadIdx.x >> 6;
    const int d = blockIdx.x * 4 + sub;
    if (d >= NN) return;
    const int g  = lane >> 4;         // edge group 0..3
    const int li = lane & 15;         // column li*4 .. +4
    const int dg = deg[d];
    const int end = cursor[d];
    const int start = end - dg;
    const int co = li * 4;
    const int dgc = (dg < 64) ? dg : 64;

    ushort4 sv = *(const ushort4*)&T[(size_t)d * 128 + co];

    if (lane < dgc) sidx[sub][lane] = nbr[start + lane];
    const int* si = sidx[sub];

    float acc[4] = {0.f, 0.f, 0.f, 0.f};
    int r = g;
    for (; r + 4 < dgc; r += 8) {
        int s0 = si[r], s1 = si[r + 4];
        ushort4 v0 = *(const ushort4*)&T[(size_t)s0 * 128 + 64 + co];
        ushort4 v1 = *(const ushort4*)&T[(size_t)s1 * 128 + 64 + co];
        acc[0] += bf2f(v0.x) + bf2f(v1.x);
        acc[1] += bf2f(v0.y) + bf2f(v1.y);
        acc[2] += bf2f(v0.z) + bf2f(v1.z);
        acc[3] += bf2f(v0.w) + bf2f(v1.w);
    }
    for (; r < dgc; r += 4) {
        int s0 = si[r];
        ushort4 v0 = *(const ushort4*)&T[(size_t)s0 * 128 + 64 + co];
        acc[0] += bf2f(v0.x); acc[1] += bf2f(v0.y);
        acc[2] += bf2f(v0.z); acc[3] += bf2f(v0.w);
    }
    for (int j = start + 64 + g; j < end; j += 4) {   // deg>64 tail
        int s0 = nbr[j];
        ushort4 v0 = *(const ushort4*)&T[(size_t)s0 * 128 + 64 + co];
        acc[0] += bf2f(v0.x); acc[1] += bf2f(v0.y);
        acc[2] += bf2f(v0.z); acc[3] += bf2f(v0.w);
    }

    #pragma unroll
    for (int i = 0; i < 4; ++i) {
        acc[i] += __shfl_xor(acc[i], 16, 64);
        acc[i] += __shfl_xor(acc[i], 32, 64);
    }

    if (g == 0) {
        const float inv = 1.0f / fmaxf((float)dg, 1.0f);
        float4 o;
        o.x = bf2f(sv.x) + acc[0] * inv;
        o.y = bf2f(sv.y) + acc[1] * inv;
        o.z = bf2f(sv.z) + acc[2] * inv;
        o.w = bf2f(sv.w) + acc[3] * inv;
        *(float4*)&out[(size_t)d * 64 + co] = o;
    }
}

extern "C" void kernel_launch(void* const* d_in, const int* in_sizes, int n_in,
                              void* d_out, int out_size, void* d_ws, size_t ws_size,
                              hipStream_t stream) {
    const float* x   = (const float*)d_in[0];
    const int*   src = (const int*)d_in[1];
    const int*   dst = (const int*)d_in[2];
    const float* Ws1 = (const float*)d_in[3];
    const float* Wn1 = (const float*)d_in[4];
    const float* b1  = (const float*)d_in[5];
    const float* Ws2 = (const float*)d_in[6];
    const float* Wn2 = (const float*)d_in[7];
    const float* b2  = (const float*)d_in[8];
    const float* Ws3 = (const float*)d_in[9];
    const float* Wn3 = (const float*)d_in[10];
    const float* b3  = (const float*)d_in[11];

    unsigned short* H1  = (unsigned short*)d_ws;
    unsigned short* H2  = H1  + (size_t)MPAD * 512;
    unsigned short* T   = H2  + (size_t)MPAD * 512;
    unsigned short* Bt1 = T   + (size_t)MPAD * 128;
    unsigned short* Bt2 = Bt1 + 256 * 512;
    unsigned short* Bt3 = Bt2 + 256 * 512;
    float* b3ext = (float*)(Bt3 + 128 * 256);
    int* deg    = (int*)(b3ext + 128);
    int* cursor = deg + 102400;
    int* nbr    = cursor + 102400;
    int* bsum   = nbr + NE;           // 100 ints (+pad)

    // CSR build (graph shared by all layers); pad region zeroed for int4 scan.
    hipMemsetAsync(deg, 0, 102400 * sizeof(int), stream);
    cast_degi<<<(NN * 64 + 255) / 256, 256, 0, stream>>>((const float4*)x, H1, dst, deg);
    scan1<<<100, 256, 0, stream>>>((const int4*)deg, (int4*)cursor, bsum);
    scan2<<<1, 64, 0, stream>>>(bsum);
    scan3<<<100, 256, 0, stream>>>((int4*)cursor, bsum);
    scatter_kernel<<<(NE + 255) / 256, 256, 0, stream>>>(src, dst, cursor, nbr);
    // cursor[d] = end offset; bucket d = nbr[end-deg .. end)

    wprep_all<<<1152, 256, 0, stream>>>(Ws1, Wn1, Ws2, Wn2, Ws3, Wn3, b3,
                                        Bt1, Bt2, Bt3, b3ext);

    const int gatherBlocks = (NN + 3) / 4;
    const dim3 g2(MPAD / 128, 2), g1(MPAD / 128, 1);

    // layer 1: H1 -> H2(left)
    gather_bf16<<<gatherBlocks, 256, 0, stream>>>(H1, nbr, cursor, deg);
    sage_mfma<16, true><<<g2, 256, 0, stream>>>(H1, Bt1, b1, H2, 512);

    // layer 2: H2 -> H1(left)
    gather_bf16<<<gatherBlocks, 256, 0, stream>>>(H2, nbr, cursor, deg);
    sage_mfma<16, true><<<g2, 256, 0, stream>>>(H2, Bt2, b2, H1, 512);

    // layer 3: T = [H1@Ws3+b3 | H1@Wn3] (K=256), then out = S + agg(P)
    sage_mfma<8, false><<<g1, 256, 0, stream>>>(H1, Bt3, b3ext, T, 128);
    final_out<<<gatherBlocks, 256, 0, stream>>>(T, nbr, cursor, deg, (float*)d_out);
}

// Round 9
// 506.387 us; speedup vs baseline: 1.1609x; 1.0268x over previous
//
#include <hip/hip_runtime.h>

// GraphSAGE 3-layer inference — R14.
//  * cast_degi restructured: 800K persistent threads x 8 float4 groups
//    (4 units of 2xfloat4 -> 1 short8 store). All 8 x-loads (128B/thread)
//    issued before converts; dst load + degree atomic fused 1:1 per thread.
//    R13's version was 1 load/1 store per thread (16B in flight) -> 1.86TB/s
//    on a streaming op; this gives 8.5KB/wave in flight and 16B stores.
//  * GEMM (R10 structure), gather, final_out, 3-pass scan, scatter,
//    wprep_all unchanged from R13.

#define NN 100000
#define NE 800000
#define MPAD 100096   // 782 * 128

typedef __attribute__((ext_vector_type(8))) short short8;
typedef __attribute__((ext_vector_type(4))) float floatx4;

__device__ __forceinline__ float bf2f(unsigned short u) {
    unsigned int x = ((unsigned int)u) << 16;
    return __builtin_bit_cast(float, x);
}
__device__ __forceinline__ unsigned short f2bf(float f) {
    unsigned int x = __builtin_bit_cast(unsigned int, f);
    x += 0x7fffu + ((x >> 16) & 1u);   // round-to-nearest-even
    return (unsigned short)(x >> 16);
}

// async global->LDS, 16B per lane. LDS dest must be wave-uniform base; HW
// writes base + lane*16. Global src is per-lane.
__device__ __forceinline__ void gl_lds16(const unsigned short* g, unsigned short* l) {
    __builtin_amdgcn_global_load_lds(
        (const __attribute__((address_space(1))) unsigned int*)g,
        (__attribute__((address_space(3))) unsigned int*)l,
        16, 0, 0);
}

// ---------------- fused cast + degree count (ILP-restructured) ----------------
// 3125 blocks x 256 = 800000 threads. Thread t: edge t's degree atomic +
// 4 units; unit k = float4 groups (2u, 2u+1), u = t + k*800000.
// 6.4M groups = 2 * 3.2M units = 4 passes * 800000.
__global__ __launch_bounds__(256) void cast_degi(const float4* __restrict__ x,
                                                 unsigned short* __restrict__ H,
                                                 const int* __restrict__ dst,
                                                 int* __restrict__ deg) {
    const int tid = blockIdx.x * 256 + threadIdx.x;   // 0..799999
    const int de = dst[tid];
    float4 a[4], b[4];
    #pragma unroll
    for (int k = 0; k < 4; ++k) {
        const int u = tid + k * 800000;
        a[k] = x[2 * (size_t)u];
        b[k] = x[2 * (size_t)u + 1];
    }
    atomicAdd(&deg[de], 1);
    #pragma unroll
    for (int k = 0; k < 4; ++k) {
        const int u = tid + k * 800000;
        const int g = 2 * u;
        const int row = g >> 6, col = (g & 63) * 4;   // col..col+8 shorts
        short8 o;
        o[0] = (short)f2bf(a[k].x); o[1] = (short)f2bf(a[k].y);
        o[2] = (short)f2bf(a[k].z); o[3] = (short)f2bf(a[k].w);
        o[4] = (short)f2bf(b[k].x); o[5] = (short)f2bf(b[k].y);
        o[6] = (short)f2bf(b[k].z); o[7] = (short)f2bf(b[k].w);
        *(short8*)&H[(size_t)row * 512 + col] = o;
    }
}

// 3-pass exclusive scan of 102400 ints (25600 int4).
__global__ __launch_bounds__(256) void scan1(const int4* __restrict__ deg4,
                                             int4* __restrict__ cur4,
                                             int* __restrict__ bsum) {
    __shared__ int woff[4];
    const int tid = threadIdx.x, lane = tid & 63, w = tid >> 6;
    const int i = blockIdx.x * 256 + tid;
    int4 v = deg4[i];
    int t = v.x + v.y + v.z + v.w;
    int s = t;
    #pragma unroll
    for (int off = 1; off < 64; off <<= 1) {
        int u = __shfl_up(s, off, 64);
        if (lane >= off) s += u;
    }
    if (lane == 63) woff[w] = s;
    __syncthreads();
    if (tid == 0) {
        int a0 = woff[0], a1 = woff[1], a2 = woff[2], a3 = woff[3];
        woff[0] = 0; woff[1] = a0; woff[2] = a0 + a1; woff[3] = a0 + a1 + a2;
        bsum[blockIdx.x] = a0 + a1 + a2 + a3;
    }
    __syncthreads();
    int excl = woff[w] + (s - t);
    int4 o;
    o.x = excl; o.y = o.x + v.x; o.z = o.y + v.y; o.w = o.z + v.z;
    cur4[i] = o;
}

__global__ void scan2(int* __restrict__ bsum) {
    const int lane = threadIdx.x;   // 64 threads
    int carry = 0;
    for (int base = 0; base < 100; base += 64) {
        int n = 100 - base; if (n > 64) n = 64;
        int v = (lane < n) ? bsum[base + lane] : 0;
        int s = v;
        #pragma unroll
        for (int off = 1; off < 64; off <<= 1) {
            int u = __shfl_up(s, off, 64);
            if (lane >= off) s += u;
        }
        int tot = __shfl(s, 63, 64);
        if (lane < n) bsum[base + lane] = carry + s - v;
        carry += tot;
    }
}

__global__ __launch_bounds__(256) void scan3(int4* __restrict__ cur4,
                                             const int* __restrict__ bsum) {
    const int i = blockIdx.x * 256 + threadIdx.x;
    const int o = bsum[blockIdx.x];
    int4 v = cur4[i];
    v.x += o; v.y += o; v.z += o; v.w += o;
    cur4[i] = v;
}

__global__ void scatter_kernel(const int* __restrict__ src, const int* __restrict__ dst,
                               int* __restrict__ cursor, int* __restrict__ nbr) {
    int e = blockIdx.x * blockDim.x + threadIdx.x;
    if (e < NE) {
        int pos = atomicAdd(&cursor[dst[e]], 1);
        nbr[pos] = src[e];
    }
}

// ---------------- fused weight prep (layers 1,2,3 in one dispatch) ----------------
__global__ __launch_bounds__(256) void wprep_all(
        const float* __restrict__ Ws1, const float* __restrict__ Wn1,
        const float* __restrict__ Ws2, const float* __restrict__ Wn2,
        const float* __restrict__ Ws3, const float* __restrict__ Wn3,
        const float* __restrict__ b3,
        unsigned short* __restrict__ Bt1, unsigned short* __restrict__ Bt2,
        unsigned short* __restrict__ Bt3, float* __restrict__ b3ext) {
    const int b = blockIdx.x;
    if (b < 1024) {
        const float* Ws = (b < 512) ? Ws1 : Ws2;
        const float* Wn = (b < 512) ? Wn1 : Wn2;
        unsigned short* Bt = (b < 512) ? Bt1 : Bt2;
        int idx = ((b & 511) << 8) + threadIdx.x;     // 0 .. 256*512
        int n = idx >> 9, k = idx & 511;
        float v = (k < 256) ? Ws[(size_t)k * 256 + n] : Wn[(size_t)(k - 256) * 256 + n];
        Bt[idx] = f2bf(v);
    } else {
        int idx = ((b - 1024) << 8) + threadIdx.x;    // 0 .. 128*256
        int n = idx >> 8, k = idx & 255;
        float v = (n < 64) ? Ws3[(size_t)k * 64 + n] : Wn3[(size_t)k * 64 + (n - 64)];
        Bt3[idx] = f2bf(v);
        if (idx < 128) b3ext[idx] = (idx < 64) ? b3[idx] : 0.f;
    }
}

// ---------------- pull-mean gather: wave/node, LDS-prefetched indices ----------------
__global__ __launch_bounds__(256) void gather_bf16(unsigned short* __restrict__ H,
                                                   const int* __restrict__ nbr,
                                                   const int* __restrict__ cursor,
                                                   const int* __restrict__ deg) {
    __shared__ int sidx[4][64];
    const int lane = threadIdx.x & 63;
    const int sub  = threadIdx.x >> 6;
    const int d = blockIdx.x * 4 + sub;
    if (d >= NN) return;
    const int dg = deg[d];
    const int end = cursor[d];
    const int start = end - dg;
    const int co = lane * 4;          // shorts 4*lane .. +4 of the 256-short left half
    const int dgc = (dg < 64) ? dg : 64;

    if (lane < dgc) sidx[sub][lane] = nbr[start + lane];
    const int* si = sidx[sub];

    float acc[4] = {0.f, 0.f, 0.f, 0.f};

    int r = 0;
    for (; r + 8 <= dgc; r += 8) {     // 8 rows (4KB) in flight
        int s0 = si[r + 0], s1 = si[r + 1], s2 = si[r + 2], s3 = si[r + 3];
        int s4 = si[r + 4], s5 = si[r + 5], s6 = si[r + 6], s7 = si[r + 7];
        ushort4 v0 = *(const ushort4*)&H[(size_t)s0 * 512 + co];
        ushort4 v1 = *(const ushort4*)&H[(size_t)s1 * 512 + co];
        ushort4 v2 = *(const ushort4*)&H[(size_t)s2 * 512 + co];
        ushort4 v3 = *(const ushort4*)&H[(size_t)s3 * 512 + co];
        ushort4 v4 = *(const ushort4*)&H[(size_t)s4 * 512 + co];
        ushort4 v5 = *(const ushort4*)&H[(size_t)s5 * 512 + co];
        ushort4 v6 = *(const ushort4*)&H[(size_t)s6 * 512 + co];
        ushort4 v7 = *(const ushort4*)&H[(size_t)s7 * 512 + co];
        acc[0] += (bf2f(v0.x) + bf2f(v1.x)) + (bf2f(v2.x) + bf2f(v3.x))
                + (bf2f(v4.x) + bf2f(v5.x)) + (bf2f(v6.x) + bf2f(v7.x));
        acc[1] += (bf2f(v0.y) + bf2f(v1.y)) + (bf2f(v2.y) + bf2f(v3.y))
                + (bf2f(v4.y) + bf2f(v5.y)) + (bf2f(v6.y) + bf2f(v7.y));
        acc[2] += (bf2f(v0.z) + bf2f(v1.z)) + (bf2f(v2.z) + bf2f(v3.z))
                + (bf2f(v4.z) + bf2f(v5.z)) + (bf2f(v6.z) + bf2f(v7.z));
        acc[3] += (bf2f(v0.w) + bf2f(v1.w)) + (bf2f(v2.w) + bf2f(v3.w))
                + (bf2f(v4.w) + bf2f(v5.w)) + (bf2f(v6.w) + bf2f(v7.w));
    }
    for (; r + 4 <= dgc; r += 4) {
        int s0 = si[r + 0], s1 = si[r + 1], s2 = si[r + 2], s3 = si[r + 3];
        ushort4 v0 = *(const ushort4*)&H[(size_t)s0 * 512 + co];
        ushort4 v1 = *(const ushort4*)&H[(size_t)s1 * 512 + co];
        ushort4 v2 = *(const ushort4*)&H[(size_t)s2 * 512 + co];
        ushort4 v3 = *(const ushort4*)&H[(size_t)s3 * 512 + co];
        acc[0] += (bf2f(v0.x) + bf2f(v1.x)) + (bf2f(v2.x) + bf2f(v3.x));
        acc[1] += (bf2f(v0.y) + bf2f(v1.y)) + (bf2f(v2.y) + bf2f(v3.y));
        acc[2] += (bf2f(v0.z) + bf2f(v1.z)) + (bf2f(v2.z) + bf2f(v3.z));
        acc[3] += (bf2f(v0.w) + bf2f(v1.w)) + (bf2f(v2.w) + bf2f(v3.w));
    }
    for (; r < dgc; ++r) {
        int s0 = si[r];
        ushort4 v0 = *(const ushort4*)&H[(size_t)s0 * 512 + co];
        acc[0] += bf2f(v0.x); acc[1] += bf2f(v0.y);
        acc[2] += bf2f(v0.z); acc[3] += bf2f(v0.w);
    }
    for (int j = start + 64; j < end; ++j) {   // deg>64 tail (practically never)
        int s0 = nbr[j];
        ushort4 v0 = *(const ushort4*)&H[(size_t)s0 * 512 + co];
        acc[0] += bf2f(v0.x); acc[1] += bf2f(v0.y);
        acc[2] += bf2f(v0.z); acc[3] += bf2f(v0.w);
    }

    const float inv = 1.0f / fmaxf((float)dg, 1.0f);
    ushort4 o;
    o.x = f2bf(acc[0] * inv); o.y = f2bf(acc[1] * inv);
    o.z = f2bf(acc[2] * inv); o.w = f2bf(acc[3] * inv);
    *(ushort4*)&H[(size_t)d * 512 + 256 + co] = o;
}

// ---------------- bf16 MFMA GEMM: BK=32 dbuf, 4 blocks/CU, slot-XOR swizzle ----------------
// C[128 x 128 per block] = A[., K] @ Bt^T + bias. KT = K/32.
template <int KT, bool RELU>
__global__ __launch_bounds__(256, 4) void sage_mfma(const unsigned short* __restrict__ A,
                                                    const unsigned short* __restrict__ Bt,
                                                    const float* __restrict__ bias,
                                                    unsigned short* __restrict__ Cout, int ldc) {
    __shared__ unsigned short lds[17408];   // 34816 B: dbuf 2x2x4096 shorts; slab 17408
    constexpr int BSTR = KT * 32;           // Bt row stride in shorts
    const int tid = threadIdx.x;
    const int lane = tid & 63;
    const int w = tid >> 6, wm = w >> 1, wn = w & 1;
    const int m0 = blockIdx.x * 128, n0 = blockIdx.y * 128;
    const int lr = lane & 15, lq = lane >> 4;

    const int sr   = lane >> 2;                       // 0..15 within 16-row chunk
    const int ssl  = (lane & 3) ^ (sr & 3);           // swizzled source slot
    const unsigned short* gA = A  + (size_t)(m0 + w * 32 + sr) * 512  + ssl * 8;
    const unsigned short* gB = Bt + (size_t)(n0 + w * 32 + sr) * BSTR + ssl * 8;

    const int lqx = (lq ^ (lr & 3)) * 8;   // read-side swizzled slot (shorts)

    floatx4 acc[4][4] = {};

    {
        unsigned short* lA = &lds[0 * 8192 + (w * 32) * 32];
        unsigned short* lB = &lds[0 * 8192 + 4096 + (w * 32) * 32];
        #pragma unroll
        for (int c = 0; c < 2; ++c) {
            gl_lds16(gA + (size_t)c * 16 * 512,  lA + c * 512);
            gl_lds16(gB + (size_t)c * 16 * BSTR, lB + c * 512);
        }
    }
    __syncthreads();

    #pragma unroll
    for (int t = 0; t < KT; ++t) {
        const int buf = t & 1;
        if (t + 1 < KT) {
            unsigned short* lA = &lds[(buf ^ 1) * 8192 + (w * 32) * 32];
            unsigned short* lB = &lds[(buf ^ 1) * 8192 + 4096 + (w * 32) * 32];
            const unsigned short* pA = gA + (size_t)(t + 1) * 32;
            const unsigned short* pB = gB + (size_t)(t + 1) * 32;
            #pragma unroll
            for (int c = 0; c < 2; ++c) {
                gl_lds16(pA + (size_t)c * 16 * 512,  lA + c * 512);
                gl_lds16(pB + (size_t)c * 16 * BSTR, lB + c * 512);
            }
        }
        const unsigned short* bA = &lds[buf * 8192];
        const unsigned short* bB = bA + 4096;
        short8 af[4], bf[4];
        #pragma unroll
        for (int mi = 0; mi < 4; ++mi)
            af[mi] = *(const short8*)&bA[(wm * 64 + mi * 16 + lr) * 32 + lqx];
        #pragma unroll
        for (int ni = 0; ni < 4; ++ni)
            bf[ni] = *(const short8*)&bB[(wn * 64 + ni * 16 + lr) * 32 + lqx];
        #pragma unroll
        for (int mi = 0; mi < 4; ++mi)
            #pragma unroll
            for (int ni = 0; ni < 4; ++ni)
                acc[mi][ni] = __builtin_amdgcn_mfma_f32_16x16x32_bf16(bf[ni], af[mi],
                                                                      acc[mi][ni], 0, 0, 0);
        __syncthreads();
    }

    unsigned short* slab = &lds[0];   // 128*136 shorts = 17408
    #pragma unroll
    for (int mi = 0; mi < 4; ++mi) {
        const int rl = wm * 64 + mi * 16 + lr;
        #pragma unroll
        for (int ni = 0; ni < 4; ++ni) {
            const int cl = wn * 64 + ni * 16 + lq * 4;
            const float4 bv = *(const float4*)&bias[n0 + cl];
            float v0 = acc[mi][ni][0] + bv.x;
            float v1 = acc[mi][ni][1] + bv.y;
            float v2 = acc[mi][ni][2] + bv.z;
            float v3 = acc[mi][ni][3] + bv.w;
            if (RELU) {
                v0 = fmaxf(v0, 0.f); v1 = fmaxf(v1, 0.f);
                v2 = fmaxf(v2, 0.f); v3 = fmaxf(v3, 0.f);
            }
            ushort4 o;
            o.x = f2bf(v0); o.y = f2bf(v1); o.z = f2bf(v2); o.w = f2bf(v3);
            *(ushort4*)&slab[rl * 136 + cl] = o;
        }
    }
    __syncthreads();
    #pragma unroll
    for (int it = 0; it < 8; ++it) {
        int idx = it * 256 + tid;
        int row = idx >> 4, c8 = (idx & 15) * 8;
        if (m0 + row < NN) {
            short8 v = *(const short8*)&slab[row * 136 + c8];
            *(short8*)&Cout[(size_t)(m0 + row) * ldc + n0 + c8] = v;
        }
    }
}

// ---------------- layer-3 finalize: out = S + mean_agg(P) ----------------
__global__ __launch_bounds__(256) void final_out(const unsigned short* __restrict__ T,
                                                 const int* __restrict__ nbr,
                                                 const int* __restrict__ cursor,
                                                 const int* __restrict__ deg,
                                                 float* __restrict__ out) {
    __shared__ int sidx[4][64];
    const int lane = threadIdx.x & 63;
    const int sub  = threadIdx.x >> 6;
    const int d = blockIdx.x * 4 + sub;
    if (d >= NN) return;
    const int g  = lane >> 4;         // edge group 0..3
    const int li = lane & 15;         // column li*4 .. +4
    const int dg = deg[d];
    const int end = cursor[d];
    const int start = end - dg;
    const int co = li * 4;
    const int dgc = (dg < 64) ? dg : 64;

    ushort4 sv = *(const ushort4*)&T[(size_t)d * 128 + co];

    if (lane < dgc) sidx[sub][lane] = nbr[start + lane];
    const int* si = sidx[sub];

    float acc[4] = {0.f, 0.f, 0.f, 0.f};
    int r = g;
    for (; r + 4 < dgc; r += 8) {
        int s0 = si[r], s1 = si[r + 4];
        ushort4 v0 = *(const ushort4*)&T[(size_t)s0 * 128 + 64 + co];
        ushort4 v1 = *(const ushort4*)&T[(size_t)s1 * 128 + 64 + co];
        acc[0] += bf2f(v0.x) + bf2f(v1.x);
        acc[1] += bf2f(v0.y) + bf2f(v1.y);
        acc[2] += bf2f(v0.z) + bf2f(v1.z);
        acc[3] += bf2f(v0.w) + bf2f(v1.w);
    }
    for (; r < dgc; r += 4) {
        int s0 = si[r];
        ushort4 v0 = *(const ushort4*)&T[(size_t)s0 * 128 + 64 + co];
        acc[0] += bf2f(v0.x); acc[1] += bf2f(v0.y);
        acc[2] += bf2f(v0.z); acc[3] += bf2f(v0.w);
    }
    for (int j = start + 64 + g; j < end; j += 4) {   // deg>64 tail
        int s0 = nbr[j];
        ushort4 v0 = *(const ushort4*)&T[(size_t)s0 * 128 + 64 + co];
        acc[0] += bf2f(v0.x); acc[1] += bf2f(v0.y);
        acc[2] += bf2f(v0.z); acc[3] += bf2f(v0.w);
    }

    #pragma unroll
    for (int i = 0; i < 4; ++i) {
        acc[i] += __shfl_xor(acc[i], 16, 64);
        acc[i] += __shfl_xor(acc[i], 32, 64);
    }

    if (g == 0) {
        const float inv = 1.0f / fmaxf((float)dg, 1.0f);
        float4 o;
        o.x = bf2f(sv.x) + acc[0] * inv;
        o.y = bf2f(sv.y) + acc[1] * inv;
        o.z = bf2f(sv.z) + acc[2] * inv;
        o.w = bf2f(sv.w) + acc[3] * inv;
        *(float4*)&out[(size_t)d * 64 + co] = o;
    }
}

extern "C" void kernel_launch(void* const* d_in, const int* in_sizes, int n_in,
                              void* d_out, int out_size, void* d_ws, size_t ws_size,
                              hipStream_t stream) {
    const float* x   = (const float*)d_in[0];
    const int*   src = (const int*)d_in[1];
    const int*   dst = (const int*)d_in[2];
    const float* Ws1 = (const float*)d_in[3];
    const float* Wn1 = (const float*)d_in[4];
    const float* b1  = (const float*)d_in[5];
    const float* Ws2 = (const float*)d_in[6];
    const float* Wn2 = (const float*)d_in[7];
    const float* b2  = (const float*)d_in[8];
    const float* Ws3 = (const float*)d_in[9];
    const float* Wn3 = (const float*)d_in[10];
    const float* b3  = (const float*)d_in[11];

    unsigned short* H1  = (unsigned short*)d_ws;
    unsigned short* H2  = H1  + (size_t)MPAD * 512;
    unsigned short* T   = H2  + (size_t)MPAD * 512;
    unsigned short* Bt1 = T   + (size_t)MPAD * 128;
    unsigned short* Bt2 = Bt1 + 256 * 512;
    unsigned short* Bt3 = Bt2 + 256 * 512;
    float* b3ext = (float*)(Bt3 + 128 * 256);
    int* deg    = (int*)(b3ext + 128);
    int* cursor = deg + 102400;
    int* nbr    = cursor + 102400;
    int* bsum   = nbr + NE;           // 100 ints (+pad)

    // CSR build (graph shared by all layers); pad region zeroed for int4 scan.
    hipMemsetAsync(deg, 0, 102400 * sizeof(int), stream);
    cast_degi<<<3125, 256, 0, stream>>>((const float4*)x, H1, dst, deg);
    scan1<<<100, 256, 0, stream>>>((const int4*)deg, (int4*)cursor, bsum);
    scan2<<<1, 64, 0, stream>>>(bsum);
    scan3<<<100, 256, 0, stream>>>((int4*)cursor, bsum);
    scatter_kernel<<<(NE + 255) / 256, 256, 0, stream>>>(src, dst, cursor, nbr);
    // cursor[d] = end offset; bucket d = nbr[end-deg .. end)

    wprep_all<<<1152, 256, 0, stream>>>(Ws1, Wn1, Ws2, Wn2, Ws3, Wn3, b3,
                                        Bt1, Bt2, Bt3, b3ext);

    const int gatherBlocks = (NN + 3) / 4;
    const dim3 g2(MPAD / 128, 2), g1(MPAD / 128, 1);

    // layer 1: H1 -> H2(left)
    gather_bf16<<<gatherBlocks, 256, 0, stream>>>(H1, nbr, cursor, deg);
    sage_mfma<16, true><<<g2, 256, 0, stream>>>(H1, Bt1, b1, H2, 512);

    // layer 2: H2 -> H1(left)
    gather_bf16<<<gatherBlocks, 256, 0, stream>>>(H2, nbr, cursor, deg);
    sage_mfma<16, true><<<g2, 256, 0, stream>>>(H2, Bt2, b2, H1, 512);

    // layer 3: T = [H1@Ws3+b3 | H1@Wn3] (K=256), then out = S + agg(P)
    sage_mfma<8, false><<<g1, 256, 0, stream>>>(H1, Bt3, b3ext, T, 128);
    final_out<<<gatherBlocks, 256, 0, stream>>>(T, nbr, cursor, deg, (float*)d_out);
}

// Round 10
// 504.900 us; speedup vs baseline: 1.1643x; 1.0029x over previous
//
#include <hip/hip_runtime.h>

// GraphSAGE 3-layer inference — R15.
//  * GEMM grid: 1D 1564 blocks with bijective XCD swizzle (m204-style) mapping
//    the two N-halves of each 128-row A-panel to CONSECUTIVE work items on the
//    SAME XCD -> second half's A-tile DMA hits that XCD's L2 instead of
//    re-fetching ~100MB from L3/HBM. (Old grid (782,2) put the pair 782 apart
//    AND on different XCDs via round-robin.) Layer 3 (single N-block) keeps
//    the plain mapping. Perf-only; correctness independent of XCD mapping.
//  * cast_degi (R14 ILP version), gather, final_out, scan, scatter, wprep_all
//    unchanged.

#define NN 100000
#define NE 800000
#define MPAD 100096   // 782 * 128

typedef __attribute__((ext_vector_type(8))) short short8;
typedef __attribute__((ext_vector_type(4))) float floatx4;

__device__ __forceinline__ float bf2f(unsigned short u) {
    unsigned int x = ((unsigned int)u) << 16;
    return __builtin_bit_cast(float, x);
}
__device__ __forceinline__ unsigned short f2bf(float f) {
    unsigned int x = __builtin_bit_cast(unsigned int, f);
    x += 0x7fffu + ((x >> 16) & 1u);   // round-to-nearest-even
    return (unsigned short)(x >> 16);
}

// async global->LDS, 16B per lane. LDS dest must be wave-uniform base; HW
// writes base + lane*16. Global src is per-lane.
__device__ __forceinline__ void gl_lds16(const unsigned short* g, unsigned short* l) {
    __builtin_amdgcn_global_load_lds(
        (const __attribute__((address_space(1))) unsigned int*)g,
        (__attribute__((address_space(3))) unsigned int*)l,
        16, 0, 0);
}

// ---------------- fused cast + degree count (ILP-restructured) ----------------
__global__ __launch_bounds__(256) void cast_degi(const float4* __restrict__ x,
                                                 unsigned short* __restrict__ H,
                                                 const int* __restrict__ dst,
                                                 int* __restrict__ deg) {
    const int tid = blockIdx.x * 256 + threadIdx.x;   // 0..799999
    const int de = dst[tid];
    float4 a[4], b[4];
    #pragma unroll
    for (int k = 0; k < 4; ++k) {
        const int u = tid + k * 800000;
        a[k] = x[2 * (size_t)u];
        b[k] = x[2 * (size_t)u + 1];
    }
    atomicAdd(&deg[de], 1);
    #pragma unroll
    for (int k = 0; k < 4; ++k) {
        const int u = tid + k * 800000;
        const int g = 2 * u;
        const int row = g >> 6, col = (g & 63) * 4;   // col..col+8 shorts
        short8 o;
        o[0] = (short)f2bf(a[k].x); o[1] = (short)f2bf(a[k].y);
        o[2] = (short)f2bf(a[k].z); o[3] = (short)f2bf(a[k].w);
        o[4] = (short)f2bf(b[k].x); o[5] = (short)f2bf(b[k].y);
        o[6] = (short)f2bf(b[k].z); o[7] = (short)f2bf(b[k].w);
        *(short8*)&H[(size_t)row * 512 + col] = o;
    }
}

// 3-pass exclusive scan of 102400 ints (25600 int4).
__global__ __launch_bounds__(256) void scan1(const int4* __restrict__ deg4,
                                             int4* __restrict__ cur4,
                                             int* __restrict__ bsum) {
    __shared__ int woff[4];
    const int tid = threadIdx.x, lane = tid & 63, w = tid >> 6;
    const int i = blockIdx.x * 256 + tid;
    int4 v = deg4[i];
    int t = v.x + v.y + v.z + v.w;
    int s = t;
    #pragma unroll
    for (int off = 1; off < 64; off <<= 1) {
        int u = __shfl_up(s, off, 64);
        if (lane >= off) s += u;
    }
    if (lane == 63) woff[w] = s;
    __syncthreads();
    if (tid == 0) {
        int a0 = woff[0], a1 = woff[1], a2 = woff[2], a3 = woff[3];
        woff[0] = 0; woff[1] = a0; woff[2] = a0 + a1; woff[3] = a0 + a1 + a2;
        bsum[blockIdx.x] = a0 + a1 + a2 + a3;
    }
    __syncthreads();
    int excl = woff[w] + (s - t);
    int4 o;
    o.x = excl; o.y = o.x + v.x; o.z = o.y + v.y; o.w = o.z + v.z;
    cur4[i] = o;
}

__global__ void scan2(int* __restrict__ bsum) {
    const int lane = threadIdx.x;   // 64 threads
    int carry = 0;
    for (int base = 0; base < 100; base += 64) {
        int n = 100 - base; if (n > 64) n = 64;
        int v = (lane < n) ? bsum[base + lane] : 0;
        int s = v;
        #pragma unroll
        for (int off = 1; off < 64; off <<= 1) {
            int u = __shfl_up(s, off, 64);
            if (lane >= off) s += u;
        }
        int tot = __shfl(s, 63, 64);
        if (lane < n) bsum[base + lane] = carry + s - v;
        carry += tot;
    }
}

__global__ __launch_bounds__(256) void scan3(int4* __restrict__ cur4,
                                             const int* __restrict__ bsum) {
    const int i = blockIdx.x * 256 + threadIdx.x;
    const int o = bsum[blockIdx.x];
    int4 v = cur4[i];
    v.x += o; v.y += o; v.z += o; v.w += o;
    cur4[i] = v;
}

__global__ void scatter_kernel(const int* __restrict__ src, const int* __restrict__ dst,
                               int* __restrict__ cursor, int* __restrict__ nbr) {
    int e = blockIdx.x * blockDim.x + threadIdx.x;
    if (e < NE) {
        int pos = atomicAdd(&cursor[dst[e]], 1);
        nbr[pos] = src[e];
    }
}

// ---------------- fused weight prep (layers 1,2,3 in one dispatch) ----------------
__global__ __launch_bounds__(256) void wprep_all(
        const float* __restrict__ Ws1, const float* __restrict__ Wn1,
        const float* __restrict__ Ws2, const float* __restrict__ Wn2,
        const float* __restrict__ Ws3, const float* __restrict__ Wn3,
        const float* __restrict__ b3,
        unsigned short* __restrict__ Bt1, unsigned short* __restrict__ Bt2,
        unsigned short* __restrict__ Bt3, float* __restrict__ b3ext) {
    const int b = blockIdx.x;
    if (b < 1024) {
        const float* Ws = (b < 512) ? Ws1 : Ws2;
        const float* Wn = (b < 512) ? Wn1 : Wn2;
        unsigned short* Bt = (b < 512) ? Bt1 : Bt2;
        int idx = ((b & 511) << 8) + threadIdx.x;     // 0 .. 256*512
        int n = idx >> 9, k = idx & 511;
        float v = (k < 256) ? Ws[(size_t)k * 256 + n] : Wn[(size_t)(k - 256) * 256 + n];
        Bt[idx] = f2bf(v);
    } else {
        int idx = ((b - 1024) << 8) + threadIdx.x;    // 0 .. 128*256
        int n = idx >> 8, k = idx & 255;
        float v = (n < 64) ? Ws3[(size_t)k * 64 + n] : Wn3[(size_t)k * 64 + (n - 64)];
        Bt3[idx] = f2bf(v);
        if (idx < 128) b3ext[idx] = (idx < 64) ? b3[idx] : 0.f;
    }
}

// ---------------- pull-mean gather: wave/node, LDS-prefetched indices ----------------
__global__ __launch_bounds__(256) void gather_bf16(unsigned short* __restrict__ H,
                                                   const int* __restrict__ nbr,
                                                   const int* __restrict__ cursor,
                                                   const int* __restrict__ deg) {
    __shared__ int sidx[4][64];
    const int lane = threadIdx.x & 63;
    const int sub  = threadIdx.x >> 6;
    const int d = blockIdx.x * 4 + sub;
    if (d >= NN) return;
    const int dg = deg[d];
    const int end = cursor[d];
    const int start = end - dg;
    const int co = lane * 4;          // shorts 4*lane .. +4 of the 256-short left half
    const int dgc = (dg < 64) ? dg : 64;

    if (lane < dgc) sidx[sub][lane] = nbr[start + lane];
    const int* si = sidx[sub];

    float acc[4] = {0.f, 0.f, 0.f, 0.f};

    int r = 0;
    for (; r + 8 <= dgc; r += 8) {     // 8 rows (4KB) in flight
        int s0 = si[r + 0], s1 = si[r + 1], s2 = si[r + 2], s3 = si[r + 3];
        int s4 = si[r + 4], s5 = si[r + 5], s6 = si[r + 6], s7 = si[r + 7];
        ushort4 v0 = *(const ushort4*)&H[(size_t)s0 * 512 + co];
        ushort4 v1 = *(const ushort4*)&H[(size_t)s1 * 512 + co];
        ushort4 v2 = *(const ushort4*)&H[(size_t)s2 * 512 + co];
        ushort4 v3 = *(const ushort4*)&H[(size_t)s3 * 512 + co];
        ushort4 v4 = *(const ushort4*)&H[(size_t)s4 * 512 + co];
        ushort4 v5 = *(const ushort4*)&H[(size_t)s5 * 512 + co];
        ushort4 v6 = *(const ushort4*)&H[(size_t)s6 * 512 + co];
        ushort4 v7 = *(const ushort4*)&H[(size_t)s7 * 512 + co];
        acc[0] += (bf2f(v0.x) + bf2f(v1.x)) + (bf2f(v2.x) + bf2f(v3.x))
                + (bf2f(v4.x) + bf2f(v5.x)) + (bf2f(v6.x) + bf2f(v7.x));
        acc[1] += (bf2f(v0.y) + bf2f(v1.y)) + (bf2f(v2.y) + bf2f(v3.y))
                + (bf2f(v4.y) + bf2f(v5.y)) + (bf2f(v6.y) + bf2f(v7.y));
        acc[2] += (bf2f(v0.z) + bf2f(v1.z)) + (bf2f(v2.z) + bf2f(v3.z))
                + (bf2f(v4.z) + bf2f(v5.z)) + (bf2f(v6.z) + bf2f(v7.z));
        acc[3] += (bf2f(v0.w) + bf2f(v1.w)) + (bf2f(v2.w) + bf2f(v3.w))
                + (bf2f(v4.w) + bf2f(v5.w)) + (bf2f(v6.w) + bf2f(v7.w));
    }
    for (; r + 4 <= dgc; r += 4) {
        int s0 = si[r + 0], s1 = si[r + 1], s2 = si[r + 2], s3 = si[r + 3];
        ushort4 v0 = *(const ushort4*)&H[(size_t)s0 * 512 + co];
        ushort4 v1 = *(const ushort4*)&H[(size_t)s1 * 512 + co];
        ushort4 v2 = *(const ushort4*)&H[(size_t)s2 * 512 + co];
        ushort4 v3 = *(const ushort4*)&H[(size_t)s3 * 512 + co];
        acc[0] += (bf2f(v0.x) + bf2f(v1.x)) + (bf2f(v2.x) + bf2f(v3.x));
        acc[1] += (bf2f(v0.y) + bf2f(v1.y)) + (bf2f(v2.y) + bf2f(v3.y));
        acc[2] += (bf2f(v0.z) + bf2f(v1.z)) + (bf2f(v2.z) + bf2f(v3.z));
        acc[3] += (bf2f(v0.w) + bf2f(v1.w)) + (bf2f(v2.w) + bf2f(v3.w));
    }
    for (; r < dgc; ++r) {
        int s0 = si[r];
        ushort4 v0 = *(const ushort4*)&H[(size_t)s0 * 512 + co];
        acc[0] += bf2f(v0.x); acc[1] += bf2f(v0.y);
        acc[2] += bf2f(v0.z); acc[3] += bf2f(v0.w);
    }
    for (int j = start + 64; j < end; ++j) {   // deg>64 tail (practically never)
        int s0 = nbr[j];
        ushort4 v0 = *(const ushort4*)&H[(size_t)s0 * 512 + co];
        acc[0] += bf2f(v0.x); acc[1] += bf2f(v0.y);
        acc[2] += bf2f(v0.z); acc[3] += bf2f(v0.w);
    }

    const float inv = 1.0f / fmaxf((float)dg, 1.0f);
    ushort4 o;
    o.x = f2bf(acc[0] * inv); o.y = f2bf(acc[1] * inv);
    o.z = f2bf(acc[2] * inv); o.w = f2bf(acc[3] * inv);
    *(ushort4*)&H[(size_t)d * 512 + 256 + co] = o;
}

// ---------------- bf16 MFMA GEMM: BK=32 dbuf, 4 blocks/CU, slot-XOR swizzle ----------------
// C[128 x 128 per block] = A[., K] @ Bt^T + bias. KT = K/32.
// PAIRED: 1564-block 1D grid; bijective XCD swizzle puts the two N-halves of
// each A-panel at consecutive positions on the same XCD (A-tile L2 reuse).
template <int KT, bool RELU, bool PAIRED>
__global__ __launch_bounds__(256, 4) void sage_mfma(const unsigned short* __restrict__ A,
                                                    const unsigned short* __restrict__ Bt,
                                                    const float* __restrict__ bias,
                                                    unsigned short* __restrict__ Cout, int ldc) {
    __shared__ unsigned short lds[17408];   // 34816 B: dbuf 2x2x4096 shorts; slab 17408
    constexpr int BSTR = KT * 32;           // Bt row stride in shorts
    const int tid = threadIdx.x;
    const int lane = tid & 63;
    const int w = tid >> 6, wm = w >> 1, wn = w & 1;

    int m0, n0;
    if (PAIRED) {
        // nwg = 1564 = 8*195 + 4; XCD x = bid%8 gets chunk of 195/196 wgids.
        constexpr int qq = 1564 / 8, rr = 1564 % 8;   // 195, 4
        const int x = blockIdx.x & 7, j = blockIdx.x >> 3;
        const int wgid = (x < rr ? x * (qq + 1) : rr * (qq + 1) + (x - rr) * qq) + j;
        m0 = (wgid >> 1) * 128;
        n0 = (wgid & 1) * 128;
    } else {
        m0 = blockIdx.x * 128;
        n0 = 0;
    }
    const int lr = lane & 15, lq = lane >> 4;

    const int sr   = lane >> 2;                       // 0..15 within 16-row chunk
    const int ssl  = (lane & 3) ^ (sr & 3);           // swizzled source slot
    const unsigned short* gA = A  + (size_t)(m0 + w * 32 + sr) * 512  + ssl * 8;
    const unsigned short* gB = Bt + (size_t)(n0 + w * 32 + sr) * BSTR + ssl * 8;

    const int lqx = (lq ^ (lr & 3)) * 8;   // read-side swizzled slot (shorts)

    floatx4 acc[4][4] = {};

    {
        unsigned short* lA = &lds[0 * 8192 + (w * 32) * 32];
        unsigned short* lB = &lds[0 * 8192 + 4096 + (w * 32) * 32];
        #pragma unroll
        for (int c = 0; c < 2; ++c) {
            gl_lds16(gA + (size_t)c * 16 * 512,  lA + c * 512);
            gl_lds16(gB + (size_t)c * 16 * BSTR, lB + c * 512);
        }
    }
    __syncthreads();

    #pragma unroll
    for (int t = 0; t < KT; ++t) {
        const int buf = t & 1;
        if (t + 1 < KT) {
            unsigned short* lA = &lds[(buf ^ 1) * 8192 + (w * 32) * 32];
            unsigned short* lB = &lds[(buf ^ 1) * 8192 + 4096 + (w * 32) * 32];
            const unsigned short* pA = gA + (size_t)(t + 1) * 32;
            const unsigned short* pB = gB + (size_t)(t + 1) * 32;
            #pragma unroll
            for (int c = 0; c < 2; ++c) {
                gl_lds16(pA + (size_t)c * 16 * 512,  lA + c * 512);
                gl_lds16(pB + (size_t)c * 16 * BSTR, lB + c * 512);
            }
        }
        const unsigned short* bA = &lds[buf * 8192];
        const unsigned short* bB = bA + 4096;
        short8 af[4], bf[4];
        #pragma unroll
        for (int mi = 0; mi < 4; ++mi)
            af[mi] = *(const short8*)&bA[(wm * 64 + mi * 16 + lr) * 32 + lqx];
        #pragma unroll
        for (int ni = 0; ni < 4; ++ni)
            bf[ni] = *(const short8*)&bB[(wn * 64 + ni * 16 + lr) * 32 + lqx];
        #pragma unroll
        for (int mi = 0; mi < 4; ++mi)
            #pragma unroll
            for (int ni = 0; ni < 4; ++ni)
                acc[mi][ni] = __builtin_amdgcn_mfma_f32_16x16x32_bf16(bf[ni], af[mi],
                                                                      acc[mi][ni], 0, 0, 0);
        __syncthreads();
    }

    unsigned short* slab = &lds[0];   // 128*136 shorts = 17408
    #pragma unroll
    for (int mi = 0; mi < 4; ++mi) {
        const int rl = wm * 64 + mi * 16 + lr;
        #pragma unroll
        for (int ni = 0; ni < 4; ++ni) {
            const int cl = wn * 64 + ni * 16 + lq * 4;
            const float4 bv = *(const float4*)&bias[n0 + cl];
            float v0 = acc[mi][ni][0] + bv.x;
            float v1 = acc[mi][ni][1] + bv.y;
            float v2 = acc[mi][ni][2] + bv.z;
            float v3 = acc[mi][ni][3] + bv.w;
            if (RELU) {
                v0 = fmaxf(v0, 0.f); v1 = fmaxf(v1, 0.f);
                v2 = fmaxf(v2, 0.f); v3 = fmaxf(v3, 0.f);
            }
            ushort4 o;
            o.x = f2bf(v0); o.y = f2bf(v1); o.z = f2bf(v2); o.w = f2bf(v3);
            *(ushort4*)&slab[rl * 136 + cl] = o;
        }
    }
    __syncthreads();
    #pragma unroll
    for (int it = 0; it < 8; ++it) {
        int idx = it * 256 + tid;
        int row = idx >> 4, c8 = (idx & 15) * 8;
        if (m0 + row < NN) {
            short8 v = *(const short8*)&slab[row * 136 + c8];
            *(short8*)&Cout[(size_t)(m0 + row) * ldc + n0 + c8] = v;
        }
    }
}

// ---------------- layer-3 finalize: out = S + mean_agg(P) ----------------
__global__ __launch_bounds__(256) void final_out(const unsigned short* __restrict__ T,
                                                 const int* __restrict__ nbr,
                                                 const int* __restrict__ cursor,
                                                 const int* __restrict__ deg,
                                                 float* __restrict__ out) {
    __shared__ int sidx[4][64];
    const int lane = threadIdx.x & 63;
    const int sub  = threadIdx.x >> 6;
    const int d = blockIdx.x * 4 + sub;
    if (d >= NN) return;
    const int g  = lane >> 4;         // edge group 0..3
    const int li = lane & 15;         // column li*4 .. +4
    const int dg = deg[d];
    const int end = cursor[d];
    const int start = end - dg;
    const int co = li * 4;
    const int dgc = (dg < 64) ? dg : 64;

    ushort4 sv = *(const ushort4*)&T[(size_t)d * 128 + co];

    if (lane < dgc) sidx[sub][lane] = nbr[start + lane];
    const int* si = sidx[sub];

    float acc[4] = {0.f, 0.f, 0.f, 0.f};
    int r = g;
    for (; r + 4 < dgc; r += 8) {
        int s0 = si[r], s1 = si[r + 4];
        ushort4 v0 = *(const ushort4*)&T[(size_t)s0 * 128 + 64 + co];
        ushort4 v1 = *(const ushort4*)&T[(size_t)s1 * 128 + 64 + co];
        acc[0] += bf2f(v0.x) + bf2f(v1.x);
        acc[1] += bf2f(v0.y) + bf2f(v1.y);
        acc[2] += bf2f(v0.z) + bf2f(v1.z);
        acc[3] += bf2f(v0.w) + bf2f(v1.w);
    }
    for (; r < dgc; r += 4) {
        int s0 = si[r];
        ushort4 v0 = *(const ushort4*)&T[(size_t)s0 * 128 + 64 + co];
        acc[0] += bf2f(v0.x); acc[1] += bf2f(v0.y);
        acc[2] += bf2f(v0.z); acc[3] += bf2f(v0.w);
    }
    for (int j = start + 64 + g; j < end; j += 4) {   // deg>64 tail
        int s0 = nbr[j];
        ushort4 v0 = *(const ushort4*)&T[(size_t)s0 * 128 + 64 + co];
        acc[0] += bf2f(v0.x); acc[1] += bf2f(v0.y);
        acc[2] += bf2f(v0.z); acc[3] += bf2f(v0.w);
    }

    #pragma unroll
    for (int i = 0; i < 4; ++i) {
        acc[i] += __shfl_xor(acc[i], 16, 64);
        acc[i] += __shfl_xor(acc[i], 32, 64);
    }

    if (g == 0) {
        const float inv = 1.0f / fmaxf((float)dg, 1.0f);
        float4 o;
        o.x = bf2f(sv.x) + acc[0] * inv;
        o.y = bf2f(sv.y) + acc[1] * inv;
        o.z = bf2f(sv.z) + acc[2] * inv;
        o.w = bf2f(sv.w) + acc[3] * inv;
        *(float4*)&out[(size_t)d * 64 + co] = o;
    }
}

extern "C" void kernel_launch(void* const* d_in, const int* in_sizes, int n_in,
                              void* d_out, int out_size, void* d_ws, size_t ws_size,
                              hipStream_t stream) {
    const float* x   = (const float*)d_in[0];
    const int*   src = (const int*)d_in[1];
    const int*   dst = (const int*)d_in[2];
    const float* Ws1 = (const float*)d_in[3];
    const float* Wn1 = (const float*)d_in[4];
    const float* b1  = (const float*)d_in[5];
    const float* Ws2 = (const float*)d_in[6];
    const float* Wn2 = (const float*)d_in[7];
    const float* b2  = (const float*)d_in[8];
    const float* Ws3 = (const float*)d_in[9];
    const float* Wn3 = (const float*)d_in[10];
    const float* b3  = (const float*)d_in[11];

    unsigned short* H1  = (unsigned short*)d_ws;
    unsigned short* H2  = H1  + (size_t)MPAD * 512;
    unsigned short* T   = H2  + (size_t)MPAD * 512;
    unsigned short* Bt1 = T   + (size_t)MPAD * 128;
    unsigned short* Bt2 = Bt1 + 256 * 512;
    unsigned short* Bt3 = Bt2 + 256 * 512;
    float* b3ext = (float*)(Bt3 + 128 * 256);
    int* deg    = (int*)(b3ext + 128);
    int* cursor = deg + 102400;
    int* nbr    = cursor + 102400;
    int* bsum   = nbr + NE;           // 100 ints (+pad)

    // CSR build (graph shared by all layers); pad region zeroed for int4 scan.
    hipMemsetAsync(deg, 0, 102400 * sizeof(int), stream);
    cast_degi<<<3125, 256, 0, stream>>>((const float4*)x, H1, dst, deg);
    scan1<<<100, 256, 0, stream>>>((const int4*)deg, (int4*)cursor, bsum);
    scan2<<<1, 64, 0, stream>>>(bsum);
    scan3<<<100, 256, 0, stream>>>((int4*)cursor, bsum);
    scatter_kernel<<<(NE + 255) / 256, 256, 0, stream>>>(src, dst, cursor, nbr);
    // cursor[d] = end offset; bucket d = nbr[end-deg .. end)

    wprep_all<<<1152, 256, 0, stream>>>(Ws1, Wn1, Ws2, Wn2, Ws3, Wn3, b3,
                                        Bt1, Bt2, Bt3, b3ext);

    const int gatherBlocks = (NN + 3) / 4;

    // layer 1: H1 -> H2(left)
    gather_bf16<<<gatherBlocks, 256, 0, stream>>>(H1, nbr, cursor, deg);
    sage_mfma<16, true, true><<<1564, 256, 0, stream>>>(H1, Bt1, b1, H2, 512);

    // layer 2: H2 -> H1(left)
    gather_bf16<<<gatherBlocks, 256, 0, stream>>>(H2, nbr, cursor, deg);
    sage_mfma<16, true, true><<<1564, 256, 0, stream>>>(H2, Bt2, b2, H1, 512);

    // layer 3: T = [H1@Ws3+b3 | H1@Wn3] (K=256), then out = S + agg(P)
    sage_mfma<8, false, false><<<782, 256, 0, stream>>>(H1, Bt3, b3ext, T, 128);
    final_out<<<gatherBlocks, 256, 0, stream>>>(T, nbr, cursor, deg, (float*)d_out);
}